// Round 9
// baseline (181.512 us; speedup 1.0000x reference)
//
#include <hip/hip_runtime.h>
#include <hip/hip_bf16.h>

#define NTOT 3145728   // 256*3*64*64
#define NIMG 768       // 256*3
#define CTAPS 1024     // GL conv truncation
#define NBAND 66       // conv bands: d = -1 .. 64

typedef __attribute__((ext_vector_type(8)))  short bf16x8;
typedef __attribute__((ext_vector_type(4)))  short bf16x4;
typedef __attribute__((ext_vector_type(8)))  unsigned short u16x8;
typedef __attribute__((ext_vector_type(4)))  unsigned short u16x4;
typedef __attribute__((ext_vector_type(4)))  float f32x4;
typedef __attribute__((ext_vector_type(16))) float f32x16;

__device__ inline unsigned short f2bf(float x) {
    unsigned u = __builtin_bit_cast(unsigned, x);
    u += 0x7fffu + ((u >> 16) & 1u);
    return (unsigned short)(u >> 16);
}
__device__ inline float bf2f(unsigned short u) {
    return __builtin_bit_cast(float, (unsigned)u << 16);
}
__device__ inline void split2(float v, unsigned short& hi, unsigned short& lo) {
    hi = f2bf(v);
    lo = f2bf(v - bf2f(hi));
}
__device__ inline bf16x8 ld2(const unsigned short* p) {   // 8B-aligned LDS read
    bf16x4 a = *(const bf16x4*)p;
    bf16x4 b = *(const bf16x4*)(p + 4);
    bf16x8 r;
    #pragma unroll
    for (int i = 0; i < 4; ++i) { r[i] = a[i]; r[4 + i] = b[i]; }
    return r;
}

// ---------------------------------------------------------------- tables ----
__global__ __launch_bounds__(1024)
void gen_tables(unsigned short* __restrict__ Tch, unsigned short* __restrict__ Tcl,
                unsigned short* __restrict__ Tsh, unsigned short* __restrict__ Tsl,
                unsigned short* __restrict__ Bth, unsigned short* __restrict__ Btl,
                unsigned short* __restrict__ fph, unsigned short* __restrict__ fpl)
{
    __shared__ float wsm[CTAPS];
    const int tid = threadIdx.x;
    const int bid = blockIdx.x;
    const float step = 6.28318530717958647692f / 64.0f;
    if (tid < 512) {
        int i = bid * 512 + tid;
        int p = i >> 6, q = i & 63;
        float ang = (float)((p * q) & 63) * step;
        unsigned short h, l;
        split2(cosf(ang), h, l); Tch[i] = h; Tcl[i] = l;
        split2(sinf(ang), h, l); Tsh[i] = h; Tsl[i] = l;
    }
    if (bid == 0) { fph[tid] = 0; fpl[tid] = 0; }   // 1024-element zero prefixes
    if (tid < 64) {
        const int l = tid;
        float vals[16];
        float local = 1.0f;
        #pragma unroll
        for (int m = 0; m < 16; ++m) {
            int j = 16 * l + 1 + m;
            local *= ((float)j - 1.5f) / (float)j;
            vals[m] = local;
        }
        float scan = local;
        #pragma unroll
        for (int d = 1; d < 64; d <<= 1) {
            float o = __shfl_up(scan, (unsigned)d, 64);
            if (l >= d) scan *= o;
        }
        float prefix = __shfl_up(scan, 1u, 64);
        if (l == 0) prefix = 1.0f;
        const float s = sqrtf((float)(NTOT - 1));
        if (l == 0) wsm[0] = s;
        #pragma unroll
        for (int m = 0; m < 16; ++m) {
            int j = 16 * l + 1 + m;
            if (j < CTAPS) wsm[j] = prefix * vals[m] * s;
        }
    }
    __syncthreads();
    const int i0 = bid * 4224;                 // 66*512/8 = 4224 per block
    for (int i = i0 + tid; i < i0 + 4224; i += 1024) {
        int d = (i >> 9) - 1, o = (i >> 4) & 31, u = i & 15;
        int j = 16 * d + o - u;
        unsigned short h = 0, l = 0;
        if (j >= 0 && j < CTAPS) split2(wsm[j], h, l);
        Bth[i] = h; Btl[i] = l;
    }
}

// ---------------------------------------------------------- MFMA 2-D DFT ---
template<int INV>
__global__ __launch_bounds__(256)
void dft_mfma(const void* __restrict__ Xin, const unsigned short* __restrict__ Xlo_in,
              const unsigned short* __restrict__ Tch, const unsigned short* __restrict__ Tcl,
              const unsigned short* __restrict__ Tsh, const unsigned short* __restrict__ Tsl,
              void* __restrict__ Out, unsigned short* __restrict__ Out2)
{
    __shared__ __align__(16) unsigned short Xh[64 * 68], Xl[64 * 68];
    __shared__ __align__(16) unsigned short Chh[64 * 68], Cll[64 * 68];
    __shared__ __align__(16) unsigned short Shh[64 * 68], Sll[64 * 68];
    const int tid = threadIdx.x;
    const int img = blockIdx.x;
    {
        const int rr = tid >> 2, c0 = (tid & 3) * 16;
        const int lb = rr * 68 + c0;
        if (!INV) {
            const float* Xf = (const float*)Xin + (size_t)img * 4096 + rr * 64 + c0;
            #pragma unroll
            for (int i = 0; i < 4; ++i) {
                float4 v = *(const float4*)(Xf + 4 * i);
                float vv[4] = {v.x, v.y, v.z, v.w};
                #pragma unroll
                for (int k = 0; k < 4; ++k) {
                    unsigned short h, l; split2(vv[k], h, l);
                    Xh[lb + 4 * i + k] = h; Xl[lb + 4 * i + k] = l;
                }
            }
        } else {
            const unsigned short* Ph = (const unsigned short*)Xin + (size_t)img * 4096 + rr * 64 + c0;
            const unsigned short* Pl = Xlo_in + (size_t)img * 4096 + rr * 64 + c0;
            #pragma unroll
            for (int i = 0; i < 4; ++i) {
                *(ushort4*)&Xh[lb + 4 * i] = *(const ushort4*)(Ph + 4 * i);
                *(ushort4*)&Xl[lb + 4 * i] = *(const ushort4*)(Pl + 4 * i);
            }
        }
    }
    __syncthreads();

    const int lane = tid & 63, wv = tid >> 6;
    const int r = lane & 31, g = lane >> 5;
    const int q0 = (wv >> 1) * 32, r0 = (wv & 1) * 32;
    const int tA = (q0 + r) * 64;     // T row base (A operand)
    const int xB = (r0 + r) * 68;     // X / C / S row base (B operand)

    f32x16 a1, a2, a3;
    // ---- row pass, cos
    #pragma unroll
    for (int i = 0; i < 16; ++i) { a1[i] = 0.f; a2[i] = 0.f; a3[i] = 0.f; }
    #pragma unroll
    for (int ks = 0; ks < 4; ++ks) {
        const int ko = ks * 16 + 8 * g;
        bf16x8 xh = ld2(&Xh[xB + ko]);
        bf16x8 xl = ld2(&Xl[xB + ko]);
        bf16x8 th = *(const bf16x8*)&Tch[tA + ko];
        bf16x8 tl = *(const bf16x8*)&Tcl[tA + ko];
        a1 = __builtin_amdgcn_mfma_f32_32x32x16_bf16(th, xh, a1, 0, 0, 0);
        a2 = __builtin_amdgcn_mfma_f32_32x32x16_bf16(th, xl, a2, 0, 0, 0);
        a3 = __builtin_amdgcn_mfma_f32_32x32x16_bf16(tl, xh, a3, 0, 0, 0);
    }
    #pragma unroll
    for (int reg = 0; reg < 16; ++reg) {
        int qq = q0 + (reg & 3) + 8 * (reg >> 2) + 4 * g;
        unsigned short h, l; split2(a1[reg] + a2[reg] + a3[reg], h, l);
        Chh[qq * 68 + r0 + r] = h; Cll[qq * 68 + r0 + r] = l;
    }
    // ---- row pass, sin (stored negated)
    #pragma unroll
    for (int i = 0; i < 16; ++i) { a1[i] = 0.f; a2[i] = 0.f; a3[i] = 0.f; }
    #pragma unroll
    for (int ks = 0; ks < 4; ++ks) {
        const int ko = ks * 16 + 8 * g;
        bf16x8 xh = ld2(&Xh[xB + ko]);
        bf16x8 xl = ld2(&Xl[xB + ko]);
        bf16x8 th = *(const bf16x8*)&Tsh[tA + ko];
        bf16x8 tl = *(const bf16x8*)&Tsl[tA + ko];
        a1 = __builtin_amdgcn_mfma_f32_32x32x16_bf16(th, xh, a1, 0, 0, 0);
        a2 = __builtin_amdgcn_mfma_f32_32x32x16_bf16(th, xl, a2, 0, 0, 0);
        a3 = __builtin_amdgcn_mfma_f32_32x32x16_bf16(tl, xh, a3, 0, 0, 0);
    }
    #pragma unroll
    for (int reg = 0; reg < 16; ++reg) {
        int qq = q0 + (reg & 3) + 8 * (reg >> 2) + 4 * g;
        unsigned short h, l; split2(-(a1[reg] + a2[reg] + a3[reg]), h, l);
        Shh[qq * 68 + r0 + r] = h; Sll[qq * 68 + r0 + r] = l;
    }
    __syncthreads();

    // ---- col pass
    #pragma unroll
    for (int i = 0; i < 16; ++i) { a1[i] = 0.f; a2[i] = 0.f; a3[i] = 0.f; }
    #pragma unroll
    for (int ks = 0; ks < 4; ++ks) {
        const int ko = ks * 16 + 8 * g;
        bf16x8 ch = ld2(&Chh[xB + ko]);
        bf16x8 cl = ld2(&Cll[xB + ko]);
        bf16x8 th = *(const bf16x8*)&Tch[tA + ko];
        bf16x8 tl = *(const bf16x8*)&Tcl[tA + ko];
        a1 = __builtin_amdgcn_mfma_f32_32x32x16_bf16(th, ch, a1, 0, 0, 0);
        a2 = __builtin_amdgcn_mfma_f32_32x32x16_bf16(th, cl, a2, 0, 0, 0);
        a3 = __builtin_amdgcn_mfma_f32_32x32x16_bf16(tl, ch, a3, 0, 0, 0);
        bf16x8 sh = ld2(&Shh[xB + ko]);
        bf16x8 sl = ld2(&Sll[xB + ko]);
        bf16x8 uh = *(const bf16x8*)&Tsh[tA + ko];
        bf16x8 ul = *(const bf16x8*)&Tsl[tA + ko];
        a1 = __builtin_amdgcn_mfma_f32_32x32x16_bf16(uh, sh, a1, 0, 0, 0);
        a2 = __builtin_amdgcn_mfma_f32_32x32x16_bf16(uh, sl, a2, 0, 0, 0);
        a3 = __builtin_amdgcn_mfma_f32_32x32x16_bf16(ul, sh, a3, 0, 0, 0);
    }
    #pragma unroll
    for (int reg = 0; reg < 16; ++reg) {
        int pp = q0 + (reg & 3) + 8 * (reg >> 2) + 4 * g;
        float v = a1[reg] + a2[reg] + a3[reg];
        size_t oi = (size_t)img * 4096 + (size_t)pp * 64 + r0 + r;
        if (INV) {
            ((float*)Out)[oi] = v * (1.0f / 4096.0f);
        } else {
            unsigned short h, l; split2(v, h, l);
            ((unsigned short*)Out)[oi] = h; Out2[oi] = l;
        }
    }
}

// ----------------------------------------------------------- MFMA conv -----
__global__ __launch_bounds__(256)
void conv_mfma(const unsigned short* __restrict__ fh, const unsigned short* __restrict__ fl,
               const unsigned short* __restrict__ Bth, const unsigned short* __restrict__ Btl,
               unsigned short* __restrict__ fr)
{
    __shared__ __align__(16) unsigned short Ah[5120], Al[5120];
    const int tid = threadIdx.x;
    const size_t tb0 = (size_t)blockIdx.x * 4096;
    {
        const unsigned short* sh = fh + tb0 - 1024;   // zero prefix covers block 0
        const unsigned short* sl = fl + tb0 - 1024;
        for (int gg = tid; gg < 640; gg += 256) {
            int off = (gg ^ ((gg >> 3) & 7)) << 3;    // swizzled element offset
            *(bf16x8*)&Ah[off] = *(const bf16x8*)(sh + gg * 8);
            *(bf16x8*)&Al[off] = *(const bf16x8*)(sl + gg * 8);
        }
    }
    __syncthreads();

    const int lane = tid & 63;
    const int wv = tid >> 6;
    const int r = lane & 31, g = lane >> 5;
    const int bo = 16 * r + 8 * g;
    const int base_gg = 128 * (wv + 1) + 4 * r + g + 2;   // A-frag group at dd=0

    f32x16 a1, a2, a3;
    #pragma unroll
    for (int i = 0; i < 16; ++i) { a1[i] = 0.f; a2[i] = 0.f; a3[i] = 0.f; }

    const unsigned short* bhp = Bth + bo;
    const unsigned short* blp = Btl + bo;
    bf16x8 bh0 = *(const bf16x8*)(bhp);
    bf16x8 bl0 = *(const bf16x8*)(blp);
    bf16x8 bh1 = *(const bf16x8*)(bhp + 512);
    bf16x8 bl1 = *(const bf16x8*)(blp + 512);

    for (int dd = 0; dd < NBAND; dd += 2) {
        bf16x8 nh0, nl0, nh1, nl1;
        if (dd + 2 < NBAND) {
            nh0 = *(const bf16x8*)(bhp + 512 * (dd + 2));
            nl0 = *(const bf16x8*)(blp + 512 * (dd + 2));
            nh1 = *(const bf16x8*)(bhp + 512 * (dd + 3));
            nl1 = *(const bf16x8*)(blp + 512 * (dd + 3));
        }
        {
            int gg = base_gg - 2 * dd;
            int off = (gg ^ ((gg >> 3) & 7)) << 3;
            bf16x8 avh = *(const bf16x8*)&Ah[off];
            bf16x8 avl = *(const bf16x8*)&Al[off];
            a1 = __builtin_amdgcn_mfma_f32_32x32x16_bf16(avh, bh0, a1, 0, 0, 0);
            a2 = __builtin_amdgcn_mfma_f32_32x32x16_bf16(avl, bh0, a2, 0, 0, 0);
            a3 = __builtin_amdgcn_mfma_f32_32x32x16_bf16(avh, bl0, a3, 0, 0, 0);
        }
        {
            int gg = base_gg - 2 * (dd + 1);
            int off = (gg ^ ((gg >> 3) & 7)) << 3;
            bf16x8 avh = *(const bf16x8*)&Ah[off];
            bf16x8 avl = *(const bf16x8*)&Al[off];
            a1 = __builtin_amdgcn_mfma_f32_32x32x16_bf16(avh, bh1, a1, 0, 0, 0);
            a2 = __builtin_amdgcn_mfma_f32_32x32x16_bf16(avl, bh1, a2, 0, 0, 0);
            a3 = __builtin_amdgcn_mfma_f32_32x32x16_bf16(avh, bl1, a3, 0, 0, 0);
        }
        bh0 = nh0; bl0 = nl0; bh1 = nh1; bl1 = nl1;
    }

    const size_t tb = tb0 + 1024 * wv;
    #pragma unroll
    for (int reg = 0; reg < 16; ++reg) {
        int row = (reg & 3) + 8 * (reg >> 2) + 4 * g;
        fr[tb + 32 * row + r] = f2bf(a1[reg] + a2[reg] + a3[reg]);
    }
}

// ------------------------------------------------------------- MFMA GEMM ----
// D = A(bf16, MxK row-major) @ W(f32, KxN row-major, converted inline).
// 128xBN tile, 4 waves, BK=32, mfma_f32_16x16x32_bf16.
// DEPTH-4 software pipeline: panel p is global-loaded at step p-4, LDS-written
// at step p-1, MFMA-consumed at step p. Barrier drains LDS only (lgkmcnt) --
// global loads stay in flight across 3+ barriers (counted vmcnt, compiler-
// generated since the 4 W/A register sets are distinct names).
// 1-D grid with XCD pairing (ids p, p+8 share a W panel on one XCD).
template<int MODE, int RELU, int BN>
__global__ __launch_bounds__(256)
void mfma_gemm(const unsigned short* __restrict__ A, const float* __restrict__ W,
               void* __restrict__ Out, const float* __restrict__ bias,
               int M, int N, int K, int kChunk, int nbn,
               unsigned short* __restrict__ Out2)
{
    constexpr int NE = (BN == 128) ? 8 : 4;   // staged k-rows per thread
    constexpr int N4 = BN / 32;               // B frags per wave
    __shared__ unsigned short Bs[2][BN * 40];
    const int tid = threadIdx.x;
    const int id = blockIdx.x;
    const int gq = id >> 4, rr = id & 15;
    const int t  = gq * 8 + (rr & 7);
    const int bm = (rr >> 3) * 128;
    const int bn = (t % nbn) * BN;
    const int z  = t / nbn;
    const int kb0 = z * kChunk;
    const int nsteps = kChunk >> 5;

    const int lane = tid & 63;
    const int wv = tid >> 6;
    const int wr = (wv >> 1) * 64, wc = (wv & 1) * (BN / 2);
    const int l15 = lane & 15, l4 = lane >> 4;

    const int sn  = (BN == 128) ? (tid & 63) * 2 : (tid & 31) * 2;
    const int skq = (BN == 128) ? (tid >> 6) * 8 : (tid >> 5) * 4;

    f32x4 acc[4][N4];
    #pragma unroll
    for (int i = 0; i < 4; ++i)
        #pragma unroll
        for (int j = 0; j < N4; ++j)
            acc[i][j] = (f32x4){0.f, 0.f, 0.f, 0.f};

    const unsigned short* Arow = A + (size_t)(bm + wr + l15) * K + l4 * 8;
    float2 Rb0[NE], Rb1[NE], Rb2[NE], Rb3[NE];
    bf16x8 fa0[4], fa1[4], fa2[4], fa3[4];

#define LOADB(R, kb) { const float* Wp_ = W + (size_t)((kb) + skq) * N + bn + sn;         \
    _Pragma("unroll") for (int e = 0; e < NE; ++e) R[e] = *(const float2*)(Wp_ + (size_t)e * N); }
#define WRITEB(R, b) {                                                                    \
    if (BN == 128) {                                                                      \
        u16x8 p0_, p1_;                                                                   \
        _Pragma("unroll") for (int e = 0; e < NE; ++e) { p0_[e] = f2bf(R[e].x); p1_[e] = f2bf(R[e].y); } \
        *(u16x8*)&Bs[b][sn * 40 + skq]       = p0_;                                       \
        *(u16x8*)&Bs[b][(sn + 1) * 40 + skq] = p1_;                                       \
    } else {                                                                              \
        u16x4 p0_, p1_;                                                                   \
        _Pragma("unroll") for (int e = 0; e < NE; ++e) { p0_[e] = f2bf(R[e].x); p1_[e] = f2bf(R[e].y); } \
        *(u16x4*)&Bs[b][sn * 40 + skq]       = p0_;                                       \
        *(u16x4*)&Bs[b][(sn + 1) * 40 + skq] = p1_;                                       \
    } }
#define LOADA(F, kb) { _Pragma("unroll") for (int m4 = 0; m4 < 4; ++m4)                   \
    F[m4] = *(const bf16x8*)(Arow + (kb) + (size_t)m4 * 16 * K); }
#define RDB(fb, b) { _Pragma("unroll") for (int n4 = 0; n4 < N4; ++n4)                    \
    fb[n4] = *(const bf16x8*)&Bs[b][(wc + n4 * 16 + l15) * 40 + l4 * 8]; }
#define BARRIER_NODRAIN asm volatile("s_waitcnt lgkmcnt(0)\ns_barrier" ::: "memory")
#define MFMA_CL(fa_, fb_) { _Pragma("unroll") for (int m4 = 0; m4 < 4; ++m4)              \
    _Pragma("unroll") for (int n4 = 0; n4 < N4; ++n4)                                     \
        acc[m4][n4] = __builtin_amdgcn_mfma_f32_16x16x32_bf16(fa_[m4], fb_[n4], acc[m4][n4], 0, 0, 0); }
// one pipeline step: at absolute step s_=s+OFS, consume panel s_ from Bs[OFS&1],
// LDS-write panel s_+1 from RBW (loaded 4 steps ago), reload RBW with panel s_+5,
// copy current A set and reload it with panel s_+4.
#define STEP(OFS, RBW, FAC) {                                                             \
    const int s_ = s + (OFS);                                                             \
    bf16x8 fb_[N4], acur_[4];                                                             \
    RDB(fb_, (OFS) & 1);                                                                  \
    if (s_ + 1 < nsteps) WRITEB(RBW, ((OFS) + 1) & 1);                                    \
    if (s_ + 5 < nsteps) LOADB(RBW, kb0 + (s_ + 5) * 32);                                 \
    _Pragma("unroll") for (int m4 = 0; m4 < 4; ++m4) acur_[m4] = FAC[m4];                 \
    if (s_ + 4 < nsteps) LOADA(FAC, kb0 + (s_ + 4) * 32);                                 \
    BARRIER_NODRAIN;                                                                      \
    MFMA_CL(acur_, fb_);                                                                  \
}

    // prologue: panel 0 -> LDS buf 0; panels 1..4 -> Rb1,Rb2,Rb3,Rb0; A 0..3.
    LOADB(Rb0, kb0);
    WRITEB(Rb0, 0);
    if (1 < nsteps) LOADB(Rb1, kb0 + 32);
    if (2 < nsteps) LOADB(Rb2, kb0 + 64);
    if (3 < nsteps) LOADB(Rb3, kb0 + 96);
    if (4 < nsteps) LOADB(Rb0, kb0 + 128);
    LOADA(fa0, kb0);
    if (1 < nsteps) LOADA(fa1, kb0 + 32);
    if (2 < nsteps) LOADA(fa2, kb0 + 64);
    if (3 < nsteps) LOADA(fa3, kb0 + 96);
    __syncthreads();

    for (int s = 0; s < nsteps; s += 4) {
        STEP(0, Rb1, fa0);
        if (s + 1 < nsteps) STEP(1, Rb2, fa1);
        if (s + 2 < nsteps) STEP(2, Rb3, fa2);
        if (s + 3 < nsteps) STEP(3, Rb0, fa3);
    }
#undef LOADB
#undef WRITEB
#undef LOADA
#undef RDB
#undef BARRIER_NODRAIN
#undef MFMA_CL
#undef STEP

    #pragma unroll
    for (int m4 = 0; m4 < 4; ++m4)
        #pragma unroll
        for (int n4 = 0; n4 < N4; ++n4) {
            const int col = bn + wc + n4 * 16 + l15;
            const int row0 = bm + wr + m4 * 16 + l4 * 4;
            #pragma unroll
            for (int rg = 0; rg < 4; ++rg) {
                float v = acc[m4][n4][rg];
                const size_t oi = (size_t)(row0 + rg) * N + col;
                if (MODE == 0) {
                    ((float*)Out)[(size_t)z * M * N + oi] = v;
                } else {
                    v += bias[col];
                    if (RELU) v = fmaxf(v, 0.f);
                    if (MODE == 1) {
                        ((float*)Out)[oi] = v;
                    } else if (MODE == 2) {
                        ((unsigned short*)Out)[oi] = f2bf(v);
                    } else {
                        unsigned short h, l; split2(v, h, l);
                        ((unsigned short*)Out)[oi] = h; Out2[oi] = l;
                    }
                }
            }
        }
}

// --------------------------------------------------------------- reduce -----
template<int RELU, int OUTBF>
__global__ __launch_bounds__(256)
void reduce_bias(const float* __restrict__ P, const float* __restrict__ bias,
                 void* __restrict__ C, int MN, int N, int S)
{
    const int idx4 = blockIdx.x * 256 + threadIdx.x;
    const int MN4 = MN >> 2;
    if (idx4 >= MN4) return;
    const float4* P4 = (const float4*)P;
    float4 a = P4[idx4];
    for (int zz = 1; zz < S; ++zz) {
        float4 b = P4[(size_t)zz * MN4 + idx4];
        a.x += b.x; a.y += b.y; a.z += b.z; a.w += b.w;
    }
    int n0 = (idx4 * 4) % N;
    a.x += bias[n0]; a.y += bias[n0 + 1]; a.z += bias[n0 + 2]; a.w += bias[n0 + 3];
    if (RELU) {
        a.x = fmaxf(a.x, 0.f); a.y = fmaxf(a.y, 0.f);
        a.z = fmaxf(a.z, 0.f); a.w = fmaxf(a.w, 0.f);
    }
    if (OUTBF) {
        ushort4 v = {f2bf(a.x), f2bf(a.y), f2bf(a.z), f2bf(a.w)};
        ((ushort4*)C)[idx4] = v;
    } else {
        ((float4*)C)[idx4] = a;
    }
}

// ---------------------------------------------------------------- launch ----
extern "C" void kernel_launch(void* const* d_in, const int* in_sizes, int n_in,
                              void* d_out, int out_size, void* d_ws, size_t ws_size,
                              hipStream_t stream)
{
    const float* x   = (const float*)d_in[0];
    const float* Ws1 = (const float*)d_in[1];
    const float* bs1 = (const float*)d_in[2];
    const float* Ws2 = (const float*)d_in[3];
    const float* bs2 = (const float*)d_in[4];
    const float* Wn1 = (const float*)d_in[5];
    const float* bn1 = (const float*)d_in[6];
    const float* Wn2 = (const float*)d_in[7];
    const float* bn2 = (const float*)d_in[8];
    const float* Wn3 = (const float*)d_in[9];
    const float* bn3 = (const float*)d_in[10];
    float* out = (float*)d_out;

    char* p = (char*)d_ws;
    auto alloc = [&](size_t bytes) { char* q = p; p += (bytes + 255) & ~(size_t)255; return q; };
    unsigned short* Tch = (unsigned short*)alloc(8192);
    unsigned short* Tcl = (unsigned short*)alloc(8192);
    unsigned short* Tsh = (unsigned short*)alloc(8192);
    unsigned short* Tsl = (unsigned short*)alloc(8192);
    unsigned short* Bth = (unsigned short*)alloc((size_t)NBAND * 512 * 2);
    unsigned short* Btl = (unsigned short*)alloc((size_t)NBAND * 512 * 2);
    unsigned short* fhb = (unsigned short*)alloc((size_t)(1024 + NTOT) * 2);
    unsigned short* flb = (unsigned short*)alloc((size_t)(1024 + NTOT) * 2);
    unsigned short* fr   = (unsigned short*)alloc((size_t)NTOT * 2);
    unsigned short* spec = (unsigned short*)alloc((size_t)NTOT * 2);
    unsigned short* ph   = (unsigned short*)alloc((size_t)NTOT * 2);
    unsigned short* pl   = (unsigned short*)alloc((size_t)NTOT * 2);
    unsigned short* t1   = (unsigned short*)alloc(262144);
    unsigned short* h1   = (unsigned short*)alloc(262144);
    unsigned short* h2   = (unsigned short*)alloc(262144);
    float* part          = (float*)alloc((size_t)32 * 131072 * 4);

    gen_tables<<<8, 1024, 0, stream>>>(Tch, Tcl, Tsh, Tsl, Bth, Btl, fhb, flb);

    // forward fft2 real part -> hi/lo bf16 f (offset 1024, zero prefix)
    dft_mfma<0><<<NIMG, 256, 0, stream>>>(x, nullptr, Tch, Tcl, Tsh, Tsl,
                                          fhb + 1024, flb + 1024);

    // GL fractional conv (banded block-GEMM, LDS-staged A) -> fr (bf16)
    conv_mfma<<<NTOT / 4096, 256, 0, stream>>>(fhb + 1024, flb + 1024, Bth, Btl, fr);

    // spectral_operator: L1 (split-K z=32, 2 blocks/CU) + reduce, L2 (N=12288)
    mfma_gemm<0, 0, 64><<<512, 256, 0, stream>>>(fr, Ws1, part, nullptr,
                                                 256, 512, 12288, 384, 8, nullptr);
    reduce_bias<1, 1><<<128, 256, 0, stream>>>(part, bs1, t1, 131072, 512, 32);
    mfma_gemm<2, 0, 64><<<384, 256, 0, stream>>>(t1, Ws2, spec, bs2,
                                                 256, 12288, 512, 512, 192, nullptr);

    // neural_operator: L3 + reduce, L4 (z=8) + reduce, L5 (N=12288, hi/lo out)
    mfma_gemm<0, 0, 64><<<512, 256, 0, stream>>>(spec, Wn1, part, nullptr,
                                                 256, 512, 12288, 384, 8, nullptr);
    reduce_bias<1, 1><<<128, 256, 0, stream>>>(part, bn1, h1, 131072, 512, 32);
    mfma_gemm<0, 0, 64><<<128, 256, 0, stream>>>(h1, Wn2, part, nullptr,
                                                 256, 512, 512, 64, 8, nullptr);
    reduce_bias<1, 1><<<128, 256, 0, stream>>>(part, bn2, h2, 131072, 512, 8);
    mfma_gemm<3, 0, 64><<<384, 256, 0, stream>>>(h2, Wn3, ph, bn3,
                                                 256, 12288, 512, 512, 192, pl);

    // inverse fft2 real part (hi/lo bf16 in, f32 out, scale 1/4096)
    dft_mfma<1><<<NIMG, 256, 0, stream>>>(ph, pl, Tch, Tcl, Tsh, Tsl, out, nullptr);
}

// Round 10
// 166.988 us; speedup vs baseline: 1.0870x; 1.0870x over previous
//
#include <hip/hip_runtime.h>
#include <hip/hip_bf16.h>

#define NTOT 3145728   // 256*3*64*64
#define NIMG 768       // 256*3
#define CTAPS 1024     // GL conv truncation
#define NBAND 66       // conv bands: d = -1 .. 64

typedef __attribute__((ext_vector_type(8)))  short bf16x8;
typedef __attribute__((ext_vector_type(4)))  short bf16x4;
typedef __attribute__((ext_vector_type(8)))  unsigned short u16x8;
typedef __attribute__((ext_vector_type(4)))  unsigned short u16x4;
typedef __attribute__((ext_vector_type(4)))  float f32x4;
typedef __attribute__((ext_vector_type(16))) float f32x16;

__device__ inline unsigned short f2bf(float x) {
    unsigned u = __builtin_bit_cast(unsigned, x);
    u += 0x7fffu + ((u >> 16) & 1u);
    return (unsigned short)(u >> 16);
}
__device__ inline float bf2f(unsigned short u) {
    return __builtin_bit_cast(float, (unsigned)u << 16);
}
__device__ inline void split2(float v, unsigned short& hi, unsigned short& lo) {
    hi = f2bf(v);
    lo = f2bf(v - bf2f(hi));
}
__device__ inline bf16x8 ld2(const unsigned short* p) {   // 8B-aligned LDS read
    bf16x4 a = *(const bf16x4*)p;
    bf16x4 b = *(const bf16x4*)(p + 4);
    bf16x8 r;
    #pragma unroll
    for (int i = 0; i < 4; ++i) { r[i] = a[i]; r[4 + i] = b[i]; }
    return r;
}

// ---------------------------------------------------------------- tables ----
__global__ __launch_bounds__(1024)
void gen_tables(unsigned short* __restrict__ Tch, unsigned short* __restrict__ Tcl,
                unsigned short* __restrict__ Tsh, unsigned short* __restrict__ Tsl,
                unsigned short* __restrict__ Bth, unsigned short* __restrict__ Btl,
                unsigned short* __restrict__ fph, unsigned short* __restrict__ fpl)
{
    __shared__ float wsm[CTAPS];
    const int tid = threadIdx.x;
    const int bid = blockIdx.x;
    const float step = 6.28318530717958647692f / 64.0f;
    if (tid < 512) {
        int i = bid * 512 + tid;
        int p = i >> 6, q = i & 63;
        float ang = (float)((p * q) & 63) * step;
        unsigned short h, l;
        split2(cosf(ang), h, l); Tch[i] = h; Tcl[i] = l;
        split2(sinf(ang), h, l); Tsh[i] = h; Tsl[i] = l;
    }
    if (bid == 0) { fph[tid] = 0; fpl[tid] = 0; }   // 1024-element zero prefixes
    if (tid < 64) {
        const int l = tid;
        float vals[16];
        float local = 1.0f;
        #pragma unroll
        for (int m = 0; m < 16; ++m) {
            int j = 16 * l + 1 + m;
            local *= ((float)j - 1.5f) / (float)j;
            vals[m] = local;
        }
        float scan = local;
        #pragma unroll
        for (int d = 1; d < 64; d <<= 1) {
            float o = __shfl_up(scan, (unsigned)d, 64);
            if (l >= d) scan *= o;
        }
        float prefix = __shfl_up(scan, 1u, 64);
        if (l == 0) prefix = 1.0f;
        const float s = sqrtf((float)(NTOT - 1));
        if (l == 0) wsm[0] = s;
        #pragma unroll
        for (int m = 0; m < 16; ++m) {
            int j = 16 * l + 1 + m;
            if (j < CTAPS) wsm[j] = prefix * vals[m] * s;
        }
    }
    __syncthreads();
    const int i0 = bid * 4224;                 // 66*512/8 = 4224 per block
    for (int i = i0 + tid; i < i0 + 4224; i += 1024) {
        int d = (i >> 9) - 1, o = (i >> 4) & 31, u = i & 15;
        int j = 16 * d + o - u;
        unsigned short h = 0, l = 0;
        if (j >= 0 && j < CTAPS) split2(wsm[j], h, l);
        Bth[i] = h; Btl[i] = l;
    }
}

// ---------------------------------------------------------- MFMA 2-D DFT ---
template<int INV>
__global__ __launch_bounds__(256)
void dft_mfma(const void* __restrict__ Xin, const unsigned short* __restrict__ Xlo_in,
              const unsigned short* __restrict__ Tch, const unsigned short* __restrict__ Tcl,
              const unsigned short* __restrict__ Tsh, const unsigned short* __restrict__ Tsl,
              void* __restrict__ Out, unsigned short* __restrict__ Out2)
{
    __shared__ __align__(16) unsigned short Xh[64 * 68], Xl[64 * 68];
    __shared__ __align__(16) unsigned short Chh[64 * 68], Cll[64 * 68];
    __shared__ __align__(16) unsigned short Shh[64 * 68], Sll[64 * 68];
    const int tid = threadIdx.x;
    const int img = blockIdx.x;
    {
        const int rr = tid >> 2, c0 = (tid & 3) * 16;
        const int lb = rr * 68 + c0;
        if (!INV) {
            const float* Xf = (const float*)Xin + (size_t)img * 4096 + rr * 64 + c0;
            #pragma unroll
            for (int i = 0; i < 4; ++i) {
                float4 v = *(const float4*)(Xf + 4 * i);
                float vv[4] = {v.x, v.y, v.z, v.w};
                #pragma unroll
                for (int k = 0; k < 4; ++k) {
                    unsigned short h, l; split2(vv[k], h, l);
                    Xh[lb + 4 * i + k] = h; Xl[lb + 4 * i + k] = l;
                }
            }
        } else {
            const unsigned short* Ph = (const unsigned short*)Xin + (size_t)img * 4096 + rr * 64 + c0;
            const unsigned short* Pl = Xlo_in + (size_t)img * 4096 + rr * 64 + c0;
            #pragma unroll
            for (int i = 0; i < 4; ++i) {
                *(ushort4*)&Xh[lb + 4 * i] = *(const ushort4*)(Ph + 4 * i);
                *(ushort4*)&Xl[lb + 4 * i] = *(const ushort4*)(Pl + 4 * i);
            }
        }
    }
    __syncthreads();

    const int lane = tid & 63, wv = tid >> 6;
    const int r = lane & 31, g = lane >> 5;
    const int q0 = (wv >> 1) * 32, r0 = (wv & 1) * 32;
    const int tA = (q0 + r) * 64;     // T row base (A operand)
    const int xB = (r0 + r) * 68;     // X / C / S row base (B operand)

    f32x16 a1, a2, a3;
    // ---- row pass, cos
    #pragma unroll
    for (int i = 0; i < 16; ++i) { a1[i] = 0.f; a2[i] = 0.f; a3[i] = 0.f; }
    #pragma unroll
    for (int ks = 0; ks < 4; ++ks) {
        const int ko = ks * 16 + 8 * g;
        bf16x8 xh = ld2(&Xh[xB + ko]);
        bf16x8 xl = ld2(&Xl[xB + ko]);
        bf16x8 th = *(const bf16x8*)&Tch[tA + ko];
        bf16x8 tl = *(const bf16x8*)&Tcl[tA + ko];
        a1 = __builtin_amdgcn_mfma_f32_32x32x16_bf16(th, xh, a1, 0, 0, 0);
        a2 = __builtin_amdgcn_mfma_f32_32x32x16_bf16(th, xl, a2, 0, 0, 0);
        a3 = __builtin_amdgcn_mfma_f32_32x32x16_bf16(tl, xh, a3, 0, 0, 0);
    }
    #pragma unroll
    for (int reg = 0; reg < 16; ++reg) {
        int qq = q0 + (reg & 3) + 8 * (reg >> 2) + 4 * g;
        unsigned short h, l; split2(a1[reg] + a2[reg] + a3[reg], h, l);
        Chh[qq * 68 + r0 + r] = h; Cll[qq * 68 + r0 + r] = l;
    }
    // ---- row pass, sin (stored negated)
    #pragma unroll
    for (int i = 0; i < 16; ++i) { a1[i] = 0.f; a2[i] = 0.f; a3[i] = 0.f; }
    #pragma unroll
    for (int ks = 0; ks < 4; ++ks) {
        const int ko = ks * 16 + 8 * g;
        bf16x8 xh = ld2(&Xh[xB + ko]);
        bf16x8 xl = ld2(&Xl[xB + ko]);
        bf16x8 th = *(const bf16x8*)&Tsh[tA + ko];
        bf16x8 tl = *(const bf16x8*)&Tsl[tA + ko];
        a1 = __builtin_amdgcn_mfma_f32_32x32x16_bf16(th, xh, a1, 0, 0, 0);
        a2 = __builtin_amdgcn_mfma_f32_32x32x16_bf16(th, xl, a2, 0, 0, 0);
        a3 = __builtin_amdgcn_mfma_f32_32x32x16_bf16(tl, xh, a3, 0, 0, 0);
    }
    #pragma unroll
    for (int reg = 0; reg < 16; ++reg) {
        int qq = q0 + (reg & 3) + 8 * (reg >> 2) + 4 * g;
        unsigned short h, l; split2(-(a1[reg] + a2[reg] + a3[reg]), h, l);
        Shh[qq * 68 + r0 + r] = h; Sll[qq * 68 + r0 + r] = l;
    }
    __syncthreads();

    // ---- col pass
    #pragma unroll
    for (int i = 0; i < 16; ++i) { a1[i] = 0.f; a2[i] = 0.f; a3[i] = 0.f; }
    #pragma unroll
    for (int ks = 0; ks < 4; ++ks) {
        const int ko = ks * 16 + 8 * g;
        bf16x8 ch = ld2(&Chh[xB + ko]);
        bf16x8 cl = ld2(&Cll[xB + ko]);
        bf16x8 th = *(const bf16x8*)&Tch[tA + ko];
        bf16x8 tl = *(const bf16x8*)&Tcl[tA + ko];
        a1 = __builtin_amdgcn_mfma_f32_32x32x16_bf16(th, ch, a1, 0, 0, 0);
        a2 = __builtin_amdgcn_mfma_f32_32x32x16_bf16(th, cl, a2, 0, 0, 0);
        a3 = __builtin_amdgcn_mfma_f32_32x32x16_bf16(tl, ch, a3, 0, 0, 0);
        bf16x8 sh = ld2(&Shh[xB + ko]);
        bf16x8 sl = ld2(&Sll[xB + ko]);
        bf16x8 uh = *(const bf16x8*)&Tsh[tA + ko];
        bf16x8 ul = *(const bf16x8*)&Tsl[tA + ko];
        a1 = __builtin_amdgcn_mfma_f32_32x32x16_bf16(uh, sh, a1, 0, 0, 0);
        a2 = __builtin_amdgcn_mfma_f32_32x32x16_bf16(uh, sl, a2, 0, 0, 0);
        a3 = __builtin_amdgcn_mfma_f32_32x32x16_bf16(ul, sh, a3, 0, 0, 0);
    }
    #pragma unroll
    for (int reg = 0; reg < 16; ++reg) {
        int pp = q0 + (reg & 3) + 8 * (reg >> 2) + 4 * g;
        float v = a1[reg] + a2[reg] + a3[reg];
        size_t oi = (size_t)img * 4096 + (size_t)pp * 64 + r0 + r;
        if (INV) {
            ((float*)Out)[oi] = v * (1.0f / 4096.0f);
        } else {
            unsigned short h, l; split2(v, h, l);
            ((unsigned short*)Out)[oi] = h; Out2[oi] = l;
        }
    }
}

// ----------------------------------------------------------- MFMA conv -----
__global__ __launch_bounds__(256)
void conv_mfma(const unsigned short* __restrict__ fh, const unsigned short* __restrict__ fl,
               const unsigned short* __restrict__ Bth, const unsigned short* __restrict__ Btl,
               unsigned short* __restrict__ fr)
{
    __shared__ __align__(16) unsigned short Ah[5120], Al[5120];
    const int tid = threadIdx.x;
    const size_t tb0 = (size_t)blockIdx.x * 4096;
    {
        const unsigned short* sh = fh + tb0 - 1024;   // zero prefix covers block 0
        const unsigned short* sl = fl + tb0 - 1024;
        for (int gg = tid; gg < 640; gg += 256) {
            int off = (gg ^ ((gg >> 3) & 7)) << 3;    // swizzled element offset
            *(bf16x8*)&Ah[off] = *(const bf16x8*)(sh + gg * 8);
            *(bf16x8*)&Al[off] = *(const bf16x8*)(sl + gg * 8);
        }
    }
    __syncthreads();

    const int lane = tid & 63;
    const int wv = tid >> 6;
    const int r = lane & 31, g = lane >> 5;
    const int bo = 16 * r + 8 * g;
    const int base_gg = 128 * (wv + 1) + 4 * r + g + 2;   // A-frag group at dd=0

    f32x16 a1, a2, a3;
    #pragma unroll
    for (int i = 0; i < 16; ++i) { a1[i] = 0.f; a2[i] = 0.f; a3[i] = 0.f; }

    const unsigned short* bhp = Bth + bo;
    const unsigned short* blp = Btl + bo;
    bf16x8 bh0 = *(const bf16x8*)(bhp);
    bf16x8 bl0 = *(const bf16x8*)(blp);
    bf16x8 bh1 = *(const bf16x8*)(bhp + 512);
    bf16x8 bl1 = *(const bf16x8*)(blp + 512);

    for (int dd = 0; dd < NBAND; dd += 2) {
        bf16x8 nh0, nl0, nh1, nl1;
        if (dd + 2 < NBAND) {
            nh0 = *(const bf16x8*)(bhp + 512 * (dd + 2));
            nl0 = *(const bf16x8*)(blp + 512 * (dd + 2));
            nh1 = *(const bf16x8*)(bhp + 512 * (dd + 3));
            nl1 = *(const bf16x8*)(blp + 512 * (dd + 3));
        }
        {
            int gg = base_gg - 2 * dd;
            int off = (gg ^ ((gg >> 3) & 7)) << 3;
            bf16x8 avh = *(const bf16x8*)&Ah[off];
            bf16x8 avl = *(const bf16x8*)&Al[off];
            a1 = __builtin_amdgcn_mfma_f32_32x32x16_bf16(avh, bh0, a1, 0, 0, 0);
            a2 = __builtin_amdgcn_mfma_f32_32x32x16_bf16(avl, bh0, a2, 0, 0, 0);
            a3 = __builtin_amdgcn_mfma_f32_32x32x16_bf16(avh, bl0, a3, 0, 0, 0);
        }
        {
            int gg = base_gg - 2 * (dd + 1);
            int off = (gg ^ ((gg >> 3) & 7)) << 3;
            bf16x8 avh = *(const bf16x8*)&Ah[off];
            bf16x8 avl = *(const bf16x8*)&Al[off];
            a1 = __builtin_amdgcn_mfma_f32_32x32x16_bf16(avh, bh1, a1, 0, 0, 0);
            a2 = __builtin_amdgcn_mfma_f32_32x32x16_bf16(avl, bh1, a2, 0, 0, 0);
            a3 = __builtin_amdgcn_mfma_f32_32x32x16_bf16(avh, bl1, a3, 0, 0, 0);
        }
        bh0 = nh0; bl0 = nl0; bh1 = nh1; bl1 = nl1;
    }

    const size_t tb = tb0 + 1024 * wv;
    #pragma unroll
    for (int reg = 0; reg < 16; ++reg) {
        int row = (reg & 3) + 8 * (reg >> 2) + 4 * g;
        fr[tb + 32 * row + r] = f2bf(a1[reg] + a2[reg] + a3[reg]);
    }
}

// ------------------------------------------------------------- MFMA GEMM ----
// D = A(bf16, MxK row-major) @ W(f32, KxN row-major, converted inline).
// BMxBN tile (BM in {64,128}), 4 waves (2x2), BK=32, mfma_f32_16x16x32_bf16.
// R8-proven depth-2 pipeline: lgkmcnt-only barrier, W regs 1 phase deep,
// A regs 2 phases deep. nsteps must be EVEN.
// 1-D grid, XCD pairing: the 256/BM bm-tiles of one W panel are ids 8 apart
// (same XCD under round-robin) -> W panel fetched once per XCD-L2.
// MODE 0: f32 partial at Out + z*M*N.  MODE 1: f32 final (+bias).
// MODE 2: bf16 final (+bias).  MODE 3: bf16 hi/lo pair final (+bias).
template<int MODE, int RELU, int BM, int BN>
__global__ __launch_bounds__(256)
void mfma_gemm(const unsigned short* __restrict__ A, const float* __restrict__ W,
               void* __restrict__ Out, const float* __restrict__ bias,
               int M, int N, int K, int kChunk, int nbn,
               unsigned short* __restrict__ Out2)
{
    constexpr int NE = (BN == 128) ? 8 : 4;   // staged k-rows per thread
    constexpr int N4 = BN / 32;               // B frags per wave
    constexpr int M4 = BM / 32;               // A frags per wave
    constexpr int GRP = 8 * (256 / BM);       // ids per panel-group (pow2)
    __shared__ unsigned short Bs[2][BN * 40];
    const int tid = threadIdx.x;
    const int id = blockIdx.x;
    const int gq = id / GRP, rr = id % GRP;
    const int t  = gq * 8 + (rr & 7);
    const int bm = (rr >> 3) * BM;
    const int bn = (t % nbn) * BN;
    const int z  = t / nbn;
    const int kb0 = z * kChunk;
    const int nsteps = kChunk >> 5;

    const int lane = tid & 63;
    const int wv = tid >> 6;
    const int wr = (wv >> 1) * (BM / 2), wc = (wv & 1) * (BN / 2);
    const int l15 = lane & 15, l4 = lane >> 4;

    const int sn  = (BN == 128) ? (tid & 63) * 2 : (tid & 31) * 2;
    const int skq = (BN == 128) ? (tid >> 6) * 8 : (tid >> 5) * 4;

    f32x4 acc[M4][N4];
    #pragma unroll
    for (int i = 0; i < M4; ++i)
        #pragma unroll
        for (int j = 0; j < N4; ++j)
            acc[i][j] = (f32x4){0.f, 0.f, 0.f, 0.f};

    const unsigned short* Arow = A + (size_t)(bm + wr + l15) * K + l4 * 8;
    float2 Rb0[NE], Rb1[NE];
    bf16x8 fa0[M4], fa1[M4];

#define LOADB(R, kb) { const float* Wp_ = W + (size_t)((kb) + skq) * N + bn + sn;         \
    _Pragma("unroll") for (int e = 0; e < NE; ++e) R[e] = *(const float2*)(Wp_ + (size_t)e * N); }
#define WRITEB(R, b) {                                                                    \
    if (BN == 128) {                                                                      \
        u16x8 p0_, p1_;                                                                   \
        _Pragma("unroll") for (int e = 0; e < NE; ++e) { p0_[e] = f2bf(R[e].x); p1_[e] = f2bf(R[e].y); } \
        *(u16x8*)&Bs[b][sn * 40 + skq]       = p0_;                                       \
        *(u16x8*)&Bs[b][(sn + 1) * 40 + skq] = p1_;                                       \
    } else {                                                                              \
        u16x4 p0_, p1_;                                                                   \
        _Pragma("unroll") for (int e = 0; e < NE; ++e) { p0_[e] = f2bf(R[e].x); p1_[e] = f2bf(R[e].y); } \
        *(u16x4*)&Bs[b][sn * 40 + skq]       = p0_;                                       \
        *(u16x4*)&Bs[b][(sn + 1) * 40 + skq] = p1_;                                       \
    } }
#define LOADA(F, kb) { _Pragma("unroll") for (int m4 = 0; m4 < M4; ++m4)                  \
    F[m4] = *(const bf16x8*)(Arow + (kb) + (size_t)m4 * 16 * K); }
#define RDB(fb, b) { _Pragma("unroll") for (int n4 = 0; n4 < N4; ++n4)                    \
    fb[n4] = *(const bf16x8*)&Bs[b][(wc + n4 * 16 + l15) * 40 + l4 * 8]; }
#define BARRIER_NODRAIN asm volatile("s_waitcnt lgkmcnt(0)\ns_barrier" ::: "memory")
#define MFMA_CL(fa_, fb_) { _Pragma("unroll") for (int m4 = 0; m4 < M4; ++m4)             \
    _Pragma("unroll") for (int n4 = 0; n4 < N4; ++n4)                                     \
        acc[m4][n4] = __builtin_amdgcn_mfma_f32_16x16x32_bf16(fa_[m4], fb_[n4], acc[m4][n4], 0, 0, 0); }

    // prologue (full drain here is fine; one-time)
    LOADB(Rb0, kb0);
    WRITEB(Rb0, 0);
    LOADB(Rb1, kb0 + 32);
    LOADA(fa0, kb0);
    LOADA(fa1, kb0 + 32);
    __syncthreads();

    for (int s = 0; s < nsteps; s += 2) {
        const int kb = kb0 + s * 32;
        {   // even step: compute panel s from Bs[0]; stage panel s+1
            bf16x8 fb[N4], acur[M4];
            RDB(fb, 0);
            WRITEB(Rb1, 1);                       // panel s+1 (always exists)
            if (s + 2 < nsteps) LOADB(Rb0, kb + 64);
            #pragma unroll
            for (int m4 = 0; m4 < M4; ++m4) acur[m4] = fa0[m4];
            if (s + 2 < nsteps) LOADA(fa0, kb + 64);
            BARRIER_NODRAIN;
            MFMA_CL(acur, fb);
        }
        {   // odd step: compute panel s+1 from Bs[1]; stage panel s+2
            bf16x8 fb[N4], acur[M4];
            RDB(fb, 1);
            if (s + 2 < nsteps) WRITEB(Rb0, 0);
            if (s + 3 < nsteps) LOADB(Rb1, kb + 96);
            #pragma unroll
            for (int m4 = 0; m4 < M4; ++m4) acur[m4] = fa1[m4];
            if (s + 3 < nsteps) LOADA(fa1, kb + 96);
            BARRIER_NODRAIN;
            MFMA_CL(acur, fb);
        }
    }
#undef LOADB
#undef WRITEB
#undef LOADA
#undef RDB
#undef BARRIER_NODRAIN
#undef MFMA_CL

    #pragma unroll
    for (int m4 = 0; m4 < M4; ++m4)
        #pragma unroll
        for (int n4 = 0; n4 < N4; ++n4) {
            const int col = bn + wc + n4 * 16 + l15;
            const int row0 = bm + wr + m4 * 16 + l4 * 4;
            #pragma unroll
            for (int rg = 0; rg < 4; ++rg) {
                float v = acc[m4][n4][rg];
                const size_t oi = (size_t)(row0 + rg) * N + col;
                if (MODE == 0) {
                    ((float*)Out)[(size_t)z * M * N + oi] = v;
                } else {
                    v += bias[col];
                    if (RELU) v = fmaxf(v, 0.f);
                    if (MODE == 1) {
                        ((float*)Out)[oi] = v;
                    } else if (MODE == 2) {
                        ((unsigned short*)Out)[oi] = f2bf(v);
                    } else {
                        unsigned short h, l; split2(v, h, l);
                        ((unsigned short*)Out)[oi] = h; Out2[oi] = l;
                    }
                }
            }
        }
}

// --------------------------------------------------------------- reduce -----
template<int RELU, int OUTBF>
__global__ __launch_bounds__(256)
void reduce_bias(const float* __restrict__ P, const float* __restrict__ bias,
                 void* __restrict__ C, int MN, int N, int S)
{
    const int idx4 = blockIdx.x * 256 + threadIdx.x;
    const int MN4 = MN >> 2;
    if (idx4 >= MN4) return;
    const float4* P4 = (const float4*)P;
    float4 a = P4[idx4];
    for (int zz = 1; zz < S; ++zz) {
        float4 b = P4[(size_t)zz * MN4 + idx4];
        a.x += b.x; a.y += b.y; a.z += b.z; a.w += b.w;
    }
    int n0 = (idx4 * 4) % N;
    a.x += bias[n0]; a.y += bias[n0 + 1]; a.z += bias[n0 + 2]; a.w += bias[n0 + 3];
    if (RELU) {
        a.x = fmaxf(a.x, 0.f); a.y = fmaxf(a.y, 0.f);
        a.z = fmaxf(a.z, 0.f); a.w = fmaxf(a.w, 0.f);
    }
    if (OUTBF) {
        ushort4 v = {f2bf(a.x), f2bf(a.y), f2bf(a.z), f2bf(a.w)};
        ((ushort4*)C)[idx4] = v;
    } else {
        ((float4*)C)[idx4] = a;
    }
}

// ---------------------------------------------------------------- launch ----
extern "C" void kernel_launch(void* const* d_in, const int* in_sizes, int n_in,
                              void* d_out, int out_size, void* d_ws, size_t ws_size,
                              hipStream_t stream)
{
    const float* x   = (const float*)d_in[0];
    const float* Ws1 = (const float*)d_in[1];
    const float* bs1 = (const float*)d_in[2];
    const float* Ws2 = (const float*)d_in[3];
    const float* bs2 = (const float*)d_in[4];
    const float* Wn1 = (const float*)d_in[5];
    const float* bn1 = (const float*)d_in[6];
    const float* Wn2 = (const float*)d_in[7];
    const float* bn2 = (const float*)d_in[8];
    const float* Wn3 = (const float*)d_in[9];
    const float* bn3 = (const float*)d_in[10];
    float* out = (float*)d_out;

    char* p = (char*)d_ws;
    auto alloc = [&](size_t bytes) { char* q = p; p += (bytes + 255) & ~(size_t)255; return q; };
    unsigned short* Tch = (unsigned short*)alloc(8192);
    unsigned short* Tcl = (unsigned short*)alloc(8192);
    unsigned short* Tsh = (unsigned short*)alloc(8192);
    unsigned short* Tsl = (unsigned short*)alloc(8192);
    unsigned short* Bth = (unsigned short*)alloc((size_t)NBAND * 512 * 2);
    unsigned short* Btl = (unsigned short*)alloc((size_t)NBAND * 512 * 2);
    unsigned short* fhb = (unsigned short*)alloc((size_t)(1024 + NTOT) * 2);
    unsigned short* flb = (unsigned short*)alloc((size_t)(1024 + NTOT) * 2);
    unsigned short* fr   = (unsigned short*)alloc((size_t)NTOT * 2);
    unsigned short* spec = (unsigned short*)alloc((size_t)NTOT * 2);
    unsigned short* ph   = (unsigned short*)alloc((size_t)NTOT * 2);
    unsigned short* pl   = (unsigned short*)alloc((size_t)NTOT * 2);
    unsigned short* t1   = (unsigned short*)alloc(262144);
    unsigned short* h1   = (unsigned short*)alloc(262144);
    unsigned short* h2   = (unsigned short*)alloc(262144);
    float* part          = (float*)alloc((size_t)16 * 131072 * 4);

    gen_tables<<<8, 1024, 0, stream>>>(Tch, Tcl, Tsh, Tsl, Bth, Btl, fhb, flb);

    // forward fft2 real part -> hi/lo bf16 f (offset 1024, zero prefix)
    dft_mfma<0><<<NIMG, 256, 0, stream>>>(x, nullptr, Tch, Tcl, Tsh, Tsl,
                                          fhb + 1024, flb + 1024);

    // GL fractional conv (banded block-GEMM, LDS-staged A) -> fr (bf16)
    conv_mfma<<<NTOT / 4096, 256, 0, stream>>>(fhb + 1024, flb + 1024, Bth, Btl, fr);

    // spectral_operator: L1 (BM=64, z=16 -> 512 blocks) + reduce, L2 (BM=64 -> 768 blocks)
    mfma_gemm<0, 0, 64, 64><<<512, 256, 0, stream>>>(fr, Ws1, part, nullptr,
                                                     256, 512, 12288, 768, 8, nullptr);
    reduce_bias<1, 1><<<128, 256, 0, stream>>>(part, bs1, t1, 131072, 512, 16);
    mfma_gemm<2, 0, 64, 64><<<768, 256, 0, stream>>>(t1, Ws2, spec, bs2,
                                                     256, 12288, 512, 512, 192, nullptr);

    // neural_operator: L3, L4 (BM=64, z=8 -> 256 blocks), L5
    mfma_gemm<0, 0, 64, 64><<<512, 256, 0, stream>>>(spec, Wn1, part, nullptr,
                                                     256, 512, 12288, 768, 8, nullptr);
    reduce_bias<1, 1><<<128, 256, 0, stream>>>(part, bn1, h1, 131072, 512, 16);
    mfma_gemm<0, 0, 64, 64><<<256, 256, 0, stream>>>(h1, Wn2, part, nullptr,
                                                     256, 512, 512, 64, 8, nullptr);
    reduce_bias<1, 1><<<128, 256, 0, stream>>>(part, bn2, h2, 131072, 512, 8);
    mfma_gemm<3, 0, 64, 64><<<768, 256, 0, stream>>>(h2, Wn3, ph, bn3,
                                                     256, 12288, 512, 512, 192, pl);

    // inverse fft2 real part (hi/lo bf16 in, f32 out, scale 1/4096)
    dft_mfma<1><<<NIMG, 256, 0, stream>>>(ph, pl, Tch, Tcl, Tsh, Tsl, out, nullptr);
}